// Round 10
// baseline (274.253 us; speedup 1.0000x reference)
//
#include <hip/hip_runtime.h>
#include <hip/hip_bf16.h>
#include <math.h>

// Problem constants (ConViT GPSA): B=16, N=576, D=1024, H=16, HD=64
#define B_ 16
#define N_ 576
#define D_ 1024
#define H_ 16
#define HD_ 64
#define BN_ (B_ * N_)   // 9216 rows
#define LOG2E 1.4426950408889634f

typedef __bf16 bf16x8 __attribute__((ext_vector_type(8)));
typedef __bf16 bf16x4 __attribute__((ext_vector_type(4)));
typedef float  f32x4  __attribute__((ext_vector_type(4)));
typedef unsigned int u32x4 __attribute__((ext_vector_type(4)));

__device__ __forceinline__ unsigned pack_bf16x2(float a, float b)
{
    __bf16 lo = (__bf16)a, hi = (__bf16)b;
    unsigned short ul = __builtin_bit_cast(unsigned short, lo);
    unsigned short uh = __builtin_bit_cast(unsigned short, hi);
    return (unsigned)ul | ((unsigned)uh << 16);
}

// ---------------------------------------------------------------------------
// fused prep kernel (one launch instead of 5):
//   region 0 (blocks 0..9215):      cast x fp32 -> xb bf16 (4 elem/thread)
//   region 1 (blocks 9216..10239):  transpose+cast W_qk|W_v -> wqkvt, W_proj -> wpt
//   region 2 (blocks 10240..12543): pos softmax -> Pp[h][n][m] bf16 (4 n/block)
// ---------------------------------------------------------------------------
__global__ __launch_bounds__(256) void prep(
    const float* __restrict__ x, const float* __restrict__ W_qk,
    const float* __restrict__ W_v, const float* __restrict__ W_proj,
    const float* __restrict__ W_pos, const float* __restrict__ gating,
    __bf16* __restrict__ xb, __bf16* __restrict__ wqkvt,
    __bf16* __restrict__ wpt, __bf16* __restrict__ Pp)
{
    __shared__ float t[64][65];
    const int bid = blockIdx.x;
    const int tid = threadIdx.x;

    if (bid < 9216) {
        size_t i = ((size_t)bid * 256 + tid) * 4;
        float4 v = *(const float4*)&x[i];
        bf16x4 o;
        o.x = (__bf16)v.x; o.y = (__bf16)v.y; o.z = (__bf16)v.z; o.w = (__bf16)v.w;
        *(bf16x4*)&xb[i] = o;
    } else if (bid < 10240) {
        int idx = bid - 9216;
        const float* W; __bf16* Wt; int N, bx, by;
        if (idx < 512)      { W = W_qk;   Wt = wqkvt;                          N = 2 * D_; bx = idx & 31; by = idx >> 5; }
        else if (idx < 768) { idx -= 512; W = W_v;    Wt = wqkvt + (size_t)2 * D_ * D_; N = D_; bx = idx & 15; by = idx >> 4; }
        else                { idx -= 768; W = W_proj; Wt = wpt;                N = D_;     bx = idx & 15; by = idx >> 4; }
        const int k0 = by * 64, n0 = bx * 64;
        const int r = tid >> 4, c4 = (tid & 15) << 2;
#pragma unroll
        for (int s = 0; s < 4; ++s) {
            int rr = r + (s << 4);
            float4 w = *(const float4*)&W[(size_t)(k0 + rr) * N + n0 + c4];
            t[rr][c4] = w.x; t[rr][c4 + 1] = w.y; t[rr][c4 + 2] = w.z; t[rr][c4 + 3] = w.w;
        }
        __syncthreads();
#pragma unroll
        for (int s = 0; s < 4; ++s) {
            int rr = r + (s << 4);
            bf16x4 o;
            o.x = (__bf16)t[c4 + 0][rr]; o.y = (__bf16)t[c4 + 1][rr];
            o.z = (__bf16)t[c4 + 2][rr]; o.w = (__bf16)t[c4 + 3][rr];
            *(bf16x4*)&Wt[(size_t)(n0 + rr) * D_ + k0 + c4] = o;
        }
    } else {
        int flat = (bid - 10240) * 4 + (tid >> 6);
        int h = flat / N_, n = flat % N_;
        int lane = tid & 63;
        const float w0 = W_pos[h] * LOG2E, w1 = W_pos[H_ + h] * LOG2E,
                    w2 = W_pos[2 * H_ + h] * LOG2E;
        const float rx = (float)(n % 24), ry = (float)(n / 24);
        float l2[9];
        float mx = -1e30f;
#pragma unroll
        for (int i = 0; i < 9; ++i) {
            int m = lane + (i << 6);
            float cx = (float)(m % 24), cy = (float)(m / 24);
            float dx = cx - rx, dy = cy - ry;
            float l = fmaf(w2, fmaf(dx, dx, dy * dy), fmaf(w0, dx, w1 * dy));
            l2[i] = l;
            mx = fmaxf(mx, l);
        }
#pragma unroll
        for (int off = 32; off; off >>= 1) mx = fmaxf(mx, __shfl_xor(mx, off, 64));
        float sum = 0.f;
#pragma unroll
        for (int i = 0; i < 9; ++i) sum += __builtin_amdgcn_exp2f(l2[i] - mx);
#pragma unroll
        for (int off = 32; off; off >>= 1) sum += __shfl_xor(sum, off, 64);
        float g = 1.f / (1.f + __expf(-gating[h]));
        float c = __log2f(g) - mx - __log2f(sum);
        __bf16* row = Pp + (size_t)(h * N_ + n) * N_;
#pragma unroll
        for (int i = 0; i < 9; ++i)
            row[(i << 6) + lane] = (__bf16)__builtin_amdgcn_exp2f(l2[i] + c);
    }
}

// ---------------------------------------------------------------------------
// 256x256 4-phase deep-pipelined bf16 MFMA GEMM, K=1024 (R9-proven).
// ---------------------------------------------------------------------------
template<int OUTMODE>
__global__ __launch_bounds__(512, 2) void gemm256(
    const __bf16* __restrict__ A, const __bf16* __restrict__ Bt,
    const float* __restrict__ bias, void* __restrict__ Cp, void* __restrict__ Cp2,
    int M, int N, int nbn)
{
    __shared__ __bf16 As[2][256 * 64];
    __shared__ __bf16 Bs[2][256 * 64];

    const int tid = threadIdx.x;
    const int lane = tid & 63, wave = tid >> 6;
    const int fr = lane & 15, quad = lane >> 4;

    // XCD-aware block swizzle (grid % 8 == 0 for both shapes)
    const int nwg = gridDim.x;
    const int wg = ((int)blockIdx.x & 7) * (nwg >> 3) + ((int)blockIdx.x >> 3);
    const int m0 = (wg / nbn) * 256;
    const int n0 = (wg % nbn) * 256;

    const int wm = (wave >> 2) * 128;
    const int wn = (wave & 3) * 64;

    int offA[2], offB[2], dA[2], dB[2];
#pragma unroll
    for (int r = 0; r < 2; ++r) {
        int rl = r * 64 + (tid >> 3);
        int pc = tid & 7;
        int l  = pc ^ (rl & 7);
        int rowA = (rl & 63) | ((rl & 64) << 1);
        int rowB = (rl & 31) + ((rl >> 5) << 6);
        offA[r] = (m0 + rowA) * 1024 + l * 8;
        offB[r] = (n0 + rowB) * 1024 + l * 8;
        int rlb = r * 64 + wave * 8;
        int rowAb = (rlb & 63) | ((rlb & 64) << 1);
        int rowBb = (rlb & 31) + ((rlb >> 5) << 6);
        dA[r] = rowAb * 64;
        dB[r] = rowBb * 64;
    }

    const int cA0 = (quad ^ (fr & 7)) * 8;
    const int cA1 = ((4 + quad) ^ (fr & 7)) * 8;

    f32x4 acc[8][4];
#pragma unroll
    for (int i = 0; i < 8; ++i)
#pragma unroll
        for (int j = 0; j < 4; ++j)
            acc[i][j] = (f32x4){0.f, 0.f, 0.f, 0.f};

    bf16x8 af[2][4];
    bf16x8 bfr[2][2][2];

#define GLL16(src, dst) __builtin_amdgcn_global_load_lds( \
    (const __attribute__((address_space(1))) void*)(src), \
    (__attribute__((address_space(3))) void*)(dst), 16, 0, 0)

#define ISSUE_A(U, BUF, KOFF) { \
    GLL16(A + offA[0] + (U) * 65536 + (KOFF), &As[BUF][dA[0] + (U) * 4096]); \
    GLL16(A + offA[1] + (U) * 65536 + (KOFF), &As[BUF][dA[1] + (U) * 4096]); }
#define ISSUE_B(U, BUF, KOFF) { \
    GLL16(Bt + offB[0] + (U) * 32768 + (KOFF), &Bs[BUF][dB[0] + (U) * 2048]); \
    GLL16(Bt + offB[1] + (U) * 32768 + (KOFF), &Bs[BUF][dB[1] + (U) * 2048]); }

#define READ_A(BUF, MH) { \
    const __bf16* _p = &As[BUF][(wm + (MH) * 64 + fr) * 64]; \
    _Pragma("unroll") for (int i = 0; i < 4; ++i) { \
        af[0][i] = *(const bf16x8*)&_p[i * 1024 + cA0]; \
        af[1][i] = *(const bf16x8*)&_p[i * 1024 + cA1]; } }

#define READ_B(BUF, NH) { \
    const __bf16* _p = &Bs[BUF][(wn + (NH) * 32 + fr) * 64]; \
    _Pragma("unroll") for (int j = 0; j < 2; ++j) { \
        bfr[NH][0][j] = *(const bf16x8*)&_p[j * 1024 + cA0]; \
        bfr[NH][1][j] = *(const bf16x8*)&_p[j * 1024 + cA1]; } }

#define MFMAQ(MH, NH) { \
    __builtin_amdgcn_s_setprio(1); \
    _Pragma("unroll") for (int i = 0; i < 4; ++i) \
    _Pragma("unroll") for (int j = 0; j < 2; ++j) { \
        f32x4 c = acc[(MH) * 4 + i][(NH) * 2 + j]; \
        c = __builtin_amdgcn_mfma_f32_16x16x32_bf16(af[0][i], bfr[NH][0][j], c, 0, 0, 0); \
        c = __builtin_amdgcn_mfma_f32_16x16x32_bf16(af[1][i], bfr[NH][1][j], c, 0, 0, 0); \
        acc[(MH) * 4 + i][(NH) * 2 + j] = c; } \
    __builtin_amdgcn_s_setprio(0); }

#define WAITV(N) asm volatile("s_waitcnt vmcnt(" #N ")" ::: "memory")
#define BARL() { asm volatile("s_waitcnt lgkmcnt(0)" ::: "memory"); \
                 asm volatile("s_barrier" ::: "memory"); }

#define ITER4(LAST) { \
  /*P1*/ ISSUE_A(0, 1, kodd); ISSUE_B(0, 1, kodd); WAITV(6); BARL(); \
        READ_A(0, 0); READ_B(0, 0); READ_B(0, 1); MFMAQ(0, 0); MFMAQ(0, 1); \
  /*P2*/ ISSUE_B(1, 1, kodd); ISSUE_A(1, 1, kodd); WAITV(8); BARL(); \
        READ_A(0, 1); MFMAQ(1, 0); MFMAQ(1, 1); \
  /*P3*/ if (!(LAST)) { ISSUE_A(0, 0, keven); ISSUE_B(0, 0, keven); WAITV(6); } \
                       else { WAITV(2); } BARL(); \
        READ_A(1, 0); READ_B(1, 0); READ_B(1, 1); MFMAQ(0, 0); MFMAQ(0, 1); \
  /*P4*/ if (!(LAST)) { ISSUE_B(1, 0, keven); ISSUE_A(1, 0, keven); WAITV(8); } \
                       else { WAITV(0); } BARL(); \
        READ_A(1, 1); MFMAQ(1, 0); MFMAQ(1, 1); }

    // prologue: stage tile0 -> buf0 in read order A0,B0,B1,A1
    ISSUE_A(0, 0, 0); ISSUE_B(0, 0, 0); ISSUE_B(1, 0, 0); ISSUE_A(1, 0, 0);

#pragma unroll 1
    for (int it = 0; it < 7; ++it) {
        const int kodd  = it * 128 + 64;
        const int keven = it * 128 + 128;
        ITER4(0);
    }
    {
        const int kodd  = 7 * 128 + 64;
        const int keven = 0;
        ITER4(1);
    }

#undef ITER4
#undef WAITV
#undef BARL
#undef MFMAQ
#undef READ_B
#undef READ_A
#undef ISSUE_B
#undef ISSUE_A
#undef GLL16

    const int colb = n0 + wn + fr;
    const int rowb = m0 + wm + quad * 4;
#pragma unroll
    for (int j = 0; j < 4; ++j) {
        int col = colb + j * 16;
        float bv = (OUTMODE == 0 && bias) ? bias[col] : 0.0f;
#pragma unroll
        for (int i = 0; i < 8; ++i) {
            int row = rowb + i * 16;
            if (OUTMODE == 3) {
                if (col < 2048) {
#pragma unroll
                    for (int t = 0; t < 4; ++t)
                        ((__bf16*)Cp)[(size_t)(row + t) * 2048 + col] = (__bf16)acc[i][j][t];
                } else {
                    int bb = row / 576;
                    int ml = row - bb * 576;
                    bf16x4 o4;
#pragma unroll
                    for (int t = 0; t < 4; ++t) o4[t] = (__bf16)acc[i][j][t];
                    *(bf16x4*)&((__bf16*)Cp2)[((size_t)bb * 1024 + (col - 2048)) * 576 + ml] = o4;
                }
            } else {
#pragma unroll
                for (int t = 0; t < 4; ++t)
                    ((float*)Cp)[(size_t)(row + t) * N + col] = acc[i][j][t] + bv;
            }
        }
    }
}

// ---------------------------------------------------------------------------
// MFMA gated attention v7: operand-swapped QK^T (S transposed, row=k col=n).
// Block = (b,h), 512 threads = 8 waves, 2/SIMD.
// Swap is free: mfma(kf, qf) uses the SAME K/Q fragments as mfma(qf, kf)
// (A-row = fr, B-col = fr, k-dim = quad*8 in both layouts). Gains:
//   - softmax per-col constants are lane-uniform (col n = fr): reduce =
//     144 in-lane ops + 2 shfl_xor (16,32) instead of 4x4 shfl groups;
//   - inv (omg/s) folds into a one-time bf16 pack (pk[72] u32; S dies as
//     pk is born, no register peak);
//   - PV B-operand built IN-REGISTER per kb: 8 __shfl (src quads 2(q&1),
//     2(q&1)+1 at same fr) + 4 cndmask (ct-select = q>>1) -- the per-kb
//     LDS write->read round-trip and its WAR serialization are GONE.
// O layout/epilogue unchanged (O row = d, col = n = fr; inv is lane-local).
// posf path unchanged. Sc now only used for the O repack.
// ---------------------------------------------------------------------------
__global__ __launch_bounds__(512, 2) void attn_mfma3(
    const __bf16* __restrict__ qk, const __bf16* __restrict__ vt,
    const __bf16* __restrict__ Pp, const float* __restrict__ gating,
    __bf16* __restrict__ ao)
{
    __shared__ __bf16 Ks[N_ * HD_];        // [n][d], phys chunk = logical ^ (n&7)
    __shared__ __bf16 Vs[HD_ * N_];        // [d][m], phys = (l&~7)|((l&7)^(d&7))
    __shared__ __bf16 Sc[8 * 16 * 56];     // per-wave scratch [16][56] (O repack)

    const int bid = blockIdx.x;
    const int h = bid & 15, b = bid >> 4;
    const int tid = threadIdx.x;
    const int lane = tid & 63, wave = tid >> 6;   // 0..7
    const int fr = lane & 15, quad = lane >> 4;

    const __bf16* qbase = qk + (size_t)b * N_ * (2 * D_) + h * HD_;
    const __bf16* kgl   = qbase + D_;
    const __bf16* vgl   = vt + (size_t)(b * H_ + h) * HD_ * N_;

#pragma unroll 3
    for (int it = 0; it < 9; ++it) {
        int s = it * 512 + tid;
        int r = s >> 3, p = s & 7;
        int l = p ^ (r & 7);
        __builtin_amdgcn_global_load_lds(
            (const __attribute__((address_space(1))) void*)(kgl + (size_t)r * (2 * D_) + l * 8),
            (__attribute__((address_space(3))) void*)&Ks[(size_t)(it * 512 + wave * 64) * 8],
            16, 0, 0);
        int d = s / 72, pv = s - d * 72;
        int lv = (pv & ~7) | ((pv & 7) ^ (d & 7));
        __builtin_amdgcn_global_load_lds(
            (const __attribute__((address_space(1))) void*)(vgl + (size_t)d * N_ + lv * 8),
            (__attribute__((address_space(3))) void*)&Vs[(size_t)(it * 512 + wave * 64) * 8],
            16, 0, 0);
    }
    __syncthreads();

    const float g   = 1.f / (1.f + __expf(-gating[h]));
    const float omg = 1.f - g;
    const float kk = 0.125f * LOG2E;

    __bf16* sw = &Sc[wave * 16 * 56];

    // shfl source lanes for the PV in-register transpose (per-lane constants)
    const int l0 = fr + 32 * (quad & 1);   // src quad 2*(q&1)
    const int l1 = l0 + 16;                // src quad 2*(q&1)+1
    const bool sel = (quad >> 1) != 0;     // ct-odd select

    for (int tt = wave; tt < 36; tt += 8) {
        const int n0 = tt * 16;

        const __bf16* qp = qbase + (size_t)(n0 + fr) * (2 * D_) + quad * 8;
        bf16x8 qf0 = *(const bf16x8*)qp;
        bf16x8 qf1 = *(const bf16x8*)(qp + 32);

        const __bf16* pprow = Pp + ((size_t)h * N_ + n0 + fr) * N_ + quad * 8;

        // ---- S^T = K @ Q^T (swapped operands): row = k, col = n = n0+fr ----
        f32x4 S[36];
#pragma unroll
        for (int ct = 0; ct < 36; ++ct) {
            int row = ct * 16 + fr;
            int p0 = quad ^ (row & 7);
            int p1 = (4 + quad) ^ (row & 7);
            bf16x8 k0 = *(const bf16x8*)&Ks[row * 64 + p0 * 8];
            bf16x8 k1 = *(const bf16x8*)&Ks[row * 64 + p1 * 8];
            f32x4 a = (f32x4){0.f, 0.f, 0.f, 0.f};
            a = __builtin_amdgcn_mfma_f32_16x16x32_bf16(k0, qf0, a, 0, 0, 0);
            a = __builtin_amdgcn_mfma_f32_16x16x32_bf16(k1, qf1, a, 0, 0, 0);
            S[ct] = a;
        }

        // ---- per-col softmax: lane-local over 144 + cross-quad shfl ----
        float m01 = -1e30f, m23 = -1e30f;
#pragma unroll
        for (int ct = 0; ct < 36; ++ct) {
            m01 = fmaxf(m01, fmaxf(S[ct][0], S[ct][1]));
            m23 = fmaxf(m23, fmaxf(S[ct][2], S[ct][3]));
        }
        float m = fmaxf(m01, m23);
        m = fmaxf(m, __shfl_xor(m, 16, 64));
        m = fmaxf(m, __shfl_xor(m, 32, 64));
        float km = kk * m;
        float s0 = 0.f, s1 = 0.f, s2 = 0.f, s3 = 0.f;
#pragma unroll
        for (int ct = 0; ct < 36; ++ct) {
            float e0 = __builtin_amdgcn_exp2f(fmaf(kk, S[ct][0], -km));
            float e1 = __builtin_amdgcn_exp2f(fmaf(kk, S[ct][1], -km));
            float e2 = __builtin_amdgcn_exp2f(fmaf(kk, S[ct][2], -km));
            float e3 = __builtin_amdgcn_exp2f(fmaf(kk, S[ct][3], -km));
            S[ct][0] = e0; S[ct][1] = e1; S[ct][2] = e2; S[ct][3] = e3;
            s0 += e0; s1 += e1; s2 += e2; s3 += e3;
        }
        float s = (s0 + s1) + (s2 + s3);
        s += __shfl_xor(s, 16, 64);
        s += __shfl_xor(s, 32, 64);
        const float inv = omg / s;     // per-lane scalar (col n = n0+fr)

        // ---- pack P = inv * exp into bf16 pairs; S dies as pk is born ----
        unsigned pk[72];
#pragma unroll
        for (int ct = 0; ct < 36; ++ct) {
            pk[2 * ct + 0] = pack_bf16x2(S[ct][0] * inv, S[ct][1] * inv);
            pk[2 * ct + 1] = pack_bf16x2(S[ct][2] * inv, S[ct][3] * inv);
        }

        // ---- PV: in-register B-operand via shfl; no LDS round-trip ----
        f32x4 O[4];
#pragma unroll
        for (int dt = 0; dt < 4; ++dt) O[dt] = (f32x4){0.f, 0.f, 0.f, 0.f};

        bf16x8 posf = *(const bf16x8*)pprow;   // kb=0 fragment
#pragma unroll
        for (int kb = 0; kb < 18; ++kb) {
            bf16x8 posf_nxt = posf;
            if (kb < 17) posf_nxt = *(const bf16x8*)(pprow + (kb + 1) * 32);
            // pull both ct words from both source quads, select by (q>>1)
            unsigned a0 = __shfl(pk[4 * kb + 0], l0, 64);
            unsigned a1 = __shfl(pk[4 * kb + 1], l0, 64);
            unsigned a2 = __shfl(pk[4 * kb + 2], l0, 64);
            unsigned a3 = __shfl(pk[4 * kb + 3], l0, 64);
            unsigned b0 = __shfl(pk[4 * kb + 0], l1, 64);
            unsigned b1 = __shfl(pk[4 * kb + 1], l1, 64);
            unsigned b2 = __shfl(pk[4 * kb + 2], l1, 64);
            unsigned b3 = __shfl(pk[4 * kb + 3], l1, 64);
            u32x4 w;
            w[0] = sel ? a2 : a0;   // e0,e1
            w[1] = sel ? a3 : a1;   // e2,e3
            w[2] = sel ? b2 : b0;   // e4,e5
            w[3] = sel ? b3 : b1;   // e6,e7
            bf16x8 pf = __builtin_bit_cast(bf16x8, w);
#pragma unroll
            for (int dt = 0; dt < 4; ++dt) {
                int d = dt * 16 + fr;
                int l = kb * 4 + quad;
                int p = (l & ~7) | ((l & 7) ^ (d & 7));
                bf16x8 vf = *(const bf16x8*)&Vs[d * 576 + p * 8];
                O[dt] = __builtin_amdgcn_mfma_f32_16x16x32_bf16(vf, pf,   O[dt], 0, 0, 0);
                O[dt] = __builtin_amdgcn_mfma_f32_16x16x32_bf16(vf, posf, O[dt], 0, 0, 0);
            }
            posf = posf_nxt;
        }

        // ---- repack O via scratch, two 32-col passes, coalesced 16B stores ----
#pragma unroll
        for (int ps = 0; ps < 2; ++ps) {
#pragma unroll
            for (int dh = 0; dh < 2; ++dh) {
                int dt = 2 * ps + dh;
                bf16x4 o4;
#pragma unroll
                for (int t = 0; t < 4; ++t) o4[t] = (__bf16)O[dt][t];
                *(bf16x4*)&sw[fr * 56 + dh * 16 + quad * 4] = o4;
            }
            asm volatile("s_waitcnt lgkmcnt(0)" ::: "memory");
            {
                int row = lane >> 2;
                int off = (lane & 3) * 8;
                bf16x8 ov = *(const bf16x8*)&sw[row * 56 + off];
                *(bf16x8*)&ao[((size_t)b * N_ + n0 + row) * D_ + h * HD_ + ps * 32 + off] = ov;
            }
            asm volatile("s_waitcnt lgkmcnt(0)" ::: "memory");
        }
    }
}

// ---------------------------------------------------------------------------
extern "C" void kernel_launch(void* const* d_in, const int* in_sizes, int n_in,
                              void* d_out, int out_size, void* d_ws, size_t ws_size,
                              hipStream_t stream)
{
    const float* x      = (const float*)d_in[0];
    const float* W_qk   = (const float*)d_in[1];
    const float* W_v    = (const float*)d_in[2];
    const float* W_proj = (const float*)d_in[3];
    const float* b_proj = (const float*)d_in[4];
    const float* W_pos  = (const float*)d_in[5];
    const float* b_pos  = (const float*)d_in[6];   // unused: cancels in softmax
    const float* gating = (const float*)d_in[7];
    const float* rel    = (const float*)d_in[8];   // unused: computed on the fly
    (void)b_pos; (void)rel;
    float* out = (float*)d_out;

    // workspace carve (~114 MB)
    char* p = (char*)d_ws;
    __bf16* xb    = (__bf16*)p;  p += (size_t)BN_ * D_ * 2;            // 18.9 MB
    __bf16* wqkvt = (__bf16*)p;  p += (size_t)(3 * D_) * D_ * 2;       //  6.3 MB
    __bf16* wpt   = (__bf16*)p;  p += (size_t)D_ * D_ * 2;             //  2.1 MB
    __bf16* qkb   = (__bf16*)p;  p += (size_t)BN_ * (2 * D_) * 2;      // 37.7 MB
    __bf16* vt    = (__bf16*)p;  p += (size_t)BN_ * D_ * 2;            // 18.9 MB [b,h,d,m]
    __bf16* aob   = (__bf16*)p;  p += (size_t)BN_ * D_ * 2;            // 18.9 MB
    __bf16* Pp    = (__bf16*)p;                                        // 10.6 MB [h,n,m]

    // fused prep: cast + 3 transposes + pos softmax (one launch)
    prep<<<12544, 256, 0, stream>>>(x, W_qk, W_v, W_proj, W_pos, gating,
                                    xb, wqkvt, wpt, Pp);
    // fused qk|v GEMM: N=3072; cols<2048 -> qkb, cols>=2048 -> vt (transposed)
    gemm256<3><<<dim3((BN_ / 256) * (3 * D_ / 256)), 512, 0, stream>>>(
        xb, wqkvt, nullptr, qkb, vt, BN_, 3 * D_, 3 * D_ / 256);
    attn_mfma3<<<B_ * H_, 512, 0, stream>>>(qkb, vt, Pp, gating, aob);
    gemm256<0><<<dim3((BN_ / 256) * (D_ / 256)), 512, 0, stream>>>(
        aob, wpt, b_proj, out, nullptr, BN_, D_, D_ / 256);
}

// Round 11
// 267.707 us; speedup vs baseline: 1.0245x; 1.0245x over previous
//
#include <hip/hip_runtime.h>
#include <hip/hip_bf16.h>
#include <math.h>

// Problem constants (ConViT GPSA): B=16, N=576, D=1024, H=16, HD=64
#define B_ 16
#define N_ 576
#define D_ 1024
#define H_ 16
#define HD_ 64
#define BN_ (B_ * N_)   // 9216 rows
#define LOG2E 1.4426950408889634f

typedef __bf16 bf16x8 __attribute__((ext_vector_type(8)));
typedef __bf16 bf16x4 __attribute__((ext_vector_type(4)));
typedef float  f32x4  __attribute__((ext_vector_type(4)));

// ---------------------------------------------------------------------------
// fused prep kernel (one launch instead of 5):
//   region 0 (blocks 0..9215):      cast x fp32 -> xb bf16 (4 elem/thread)
//   region 1 (blocks 9216..10239):  transpose+cast W_qk|W_v -> wqkvt, W_proj -> wpt
//   region 2 (blocks 10240..12543): pos softmax -> Pp[h][n][m] bf16 (4 n/block)
// ---------------------------------------------------------------------------
__global__ __launch_bounds__(256) void prep(
    const float* __restrict__ x, const float* __restrict__ W_qk,
    const float* __restrict__ W_v, const float* __restrict__ W_proj,
    const float* __restrict__ W_pos, const float* __restrict__ gating,
    __bf16* __restrict__ xb, __bf16* __restrict__ wqkvt,
    __bf16* __restrict__ wpt, __bf16* __restrict__ Pp)
{
    __shared__ float t[64][65];
    const int bid = blockIdx.x;
    const int tid = threadIdx.x;

    if (bid < 9216) {
        size_t i = ((size_t)bid * 256 + tid) * 4;
        float4 v = *(const float4*)&x[i];
        bf16x4 o;
        o.x = (__bf16)v.x; o.y = (__bf16)v.y; o.z = (__bf16)v.z; o.w = (__bf16)v.w;
        *(bf16x4*)&xb[i] = o;
    } else if (bid < 10240) {
        int idx = bid - 9216;
        const float* W; __bf16* Wt; int N, bx, by;
        if (idx < 512)      { W = W_qk;   Wt = wqkvt;                          N = 2 * D_; bx = idx & 31; by = idx >> 5; }
        else if (idx < 768) { idx -= 512; W = W_v;    Wt = wqkvt + (size_t)2 * D_ * D_; N = D_; bx = idx & 15; by = idx >> 4; }
        else                { idx -= 768; W = W_proj; Wt = wpt;                N = D_;     bx = idx & 15; by = idx >> 4; }
        const int k0 = by * 64, n0 = bx * 64;
        const int r = tid >> 4, c4 = (tid & 15) << 2;
#pragma unroll
        for (int s = 0; s < 4; ++s) {
            int rr = r + (s << 4);
            float4 w = *(const float4*)&W[(size_t)(k0 + rr) * N + n0 + c4];
            t[rr][c4] = w.x; t[rr][c4 + 1] = w.y; t[rr][c4 + 2] = w.z; t[rr][c4 + 3] = w.w;
        }
        __syncthreads();
#pragma unroll
        for (int s = 0; s < 4; ++s) {
            int rr = r + (s << 4);
            bf16x4 o;
            o.x = (__bf16)t[c4 + 0][rr]; o.y = (__bf16)t[c4 + 1][rr];
            o.z = (__bf16)t[c4 + 2][rr]; o.w = (__bf16)t[c4 + 3][rr];
            *(bf16x4*)&Wt[(size_t)(n0 + rr) * D_ + k0 + c4] = o;
        }
    } else {
        int flat = (bid - 10240) * 4 + (tid >> 6);
        int h = flat / N_, n = flat % N_;
        int lane = tid & 63;
        const float w0 = W_pos[h] * LOG2E, w1 = W_pos[H_ + h] * LOG2E,
                    w2 = W_pos[2 * H_ + h] * LOG2E;
        const float rx = (float)(n % 24), ry = (float)(n / 24);
        float l2[9];
        float mx = -1e30f;
#pragma unroll
        for (int i = 0; i < 9; ++i) {
            int m = lane + (i << 6);
            float cx = (float)(m % 24), cy = (float)(m / 24);
            float dx = cx - rx, dy = cy - ry;
            float l = fmaf(w2, fmaf(dx, dx, dy * dy), fmaf(w0, dx, w1 * dy));
            l2[i] = l;
            mx = fmaxf(mx, l);
        }
#pragma unroll
        for (int off = 32; off; off >>= 1) mx = fmaxf(mx, __shfl_xor(mx, off, 64));
        float sum = 0.f;
#pragma unroll
        for (int i = 0; i < 9; ++i) sum += __builtin_amdgcn_exp2f(l2[i] - mx);
#pragma unroll
        for (int off = 32; off; off >>= 1) sum += __shfl_xor(sum, off, 64);
        float g = 1.f / (1.f + __expf(-gating[h]));
        float c = __log2f(g) - mx - __log2f(sum);
        __bf16* row = Pp + (size_t)(h * N_ + n) * N_;
#pragma unroll
        for (int i = 0; i < 9; ++i)
            row[(i << 6) + lane] = (__bf16)__builtin_amdgcn_exp2f(l2[i] + c);
    }
}

// ---------------------------------------------------------------------------
// 256x256 4-phase deep-pipelined bf16 MFMA GEMM, K=1024 (R9-proven schedule).
// R11: LDS-staged transpose epilogue for the vt half (OUTMODE 3, n0>=2048).
// The old direct vt store was 8B fragments at 1152B lane stride -> partial
// 64B lines -> measured WRITE_SIZE 90 MB vs 56.6 ideal (~2.8x amplification
// on vt's 18.9 MB). After the K-loop the staging LDS is dead: restage the
// 256(m)x256(d) acc as T[d][m] (stride 264 bf16, 2-way banked = free), then
// write out 16B-contiguous runs, 512B coalesced per 32-thread group. Runs
// are 8-aligned and 576%8==0 so no run crosses a batch boundary.
// SMEM = one 135168B array: As|Bs dbuf (128K) aliased with T (132K).
// OUTMODE: 0 = fp32 C[M,N]+bias; 3 = fused qk|v split (see launch).
// ---------------------------------------------------------------------------
template<int OUTMODE>
__global__ __launch_bounds__(512, 2) void gemm256(
    const __bf16* __restrict__ A, const __bf16* __restrict__ Bt,
    const float* __restrict__ bias, void* __restrict__ Cp, void* __restrict__ Cp2,
    int M, int N, int nbn)
{
    __shared__ __bf16 SMEM[67584];   // 135168 B

    const int tid = threadIdx.x;
    const int lane = tid & 63, wave = tid >> 6;
    const int fr = lane & 15, quad = lane >> 4;

    // XCD-aware block swizzle (grid % 8 == 0 for both shapes)
    const int nwg = gridDim.x;
    const int wg = ((int)blockIdx.x & 7) * (nwg >> 3) + ((int)blockIdx.x >> 3);
    const int m0 = (wg / nbn) * 256;
    const int n0 = (wg % nbn) * 256;

    const int wm = (wave >> 2) * 128;
    const int wn = (wave & 3) * 64;

    int offA[2], offB[2], dA[2], dB[2];
#pragma unroll
    for (int r = 0; r < 2; ++r) {
        int rl = r * 64 + (tid >> 3);
        int pc = tid & 7;
        int l  = pc ^ (rl & 7);
        int rowA = (rl & 63) | ((rl & 64) << 1);
        int rowB = (rl & 31) + ((rl >> 5) << 6);
        offA[r] = (m0 + rowA) * 1024 + l * 8;
        offB[r] = (n0 + rowB) * 1024 + l * 8;
        int rlb = r * 64 + wave * 8;
        int rowAb = (rlb & 63) | ((rlb & 64) << 1);
        int rowBb = (rlb & 31) + ((rlb >> 5) << 6);
        dA[r] = rowAb * 64;
        dB[r] = rowBb * 64;
    }

    const int cA0 = (quad ^ (fr & 7)) * 8;
    const int cA1 = ((4 + quad) ^ (fr & 7)) * 8;

    f32x4 acc[8][4];
#pragma unroll
    for (int i = 0; i < 8; ++i)
#pragma unroll
        for (int j = 0; j < 4; ++j)
            acc[i][j] = (f32x4){0.f, 0.f, 0.f, 0.f};

    bf16x8 af[2][4];
    bf16x8 bfr[2][2][2];

#define GLL16(src, dst) __builtin_amdgcn_global_load_lds( \
    (const __attribute__((address_space(1))) void*)(src), \
    (__attribute__((address_space(3))) void*)(dst), 16, 0, 0)

#define ISSUE_A(U, BUF, KOFF) { \
    GLL16(A + offA[0] + (U) * 65536 + (KOFF), &SMEM[(BUF) * 16384 + dA[0] + (U) * 4096]); \
    GLL16(A + offA[1] + (U) * 65536 + (KOFF), &SMEM[(BUF) * 16384 + dA[1] + (U) * 4096]); }
#define ISSUE_B(U, BUF, KOFF) { \
    GLL16(Bt + offB[0] + (U) * 32768 + (KOFF), &SMEM[32768 + (BUF) * 16384 + dB[0] + (U) * 2048]); \
    GLL16(Bt + offB[1] + (U) * 32768 + (KOFF), &SMEM[32768 + (BUF) * 16384 + dB[1] + (U) * 2048]); }

#define READ_A(BUF, MH) { \
    const __bf16* _p = &SMEM[(BUF) * 16384 + (wm + (MH) * 64 + fr) * 64]; \
    _Pragma("unroll") for (int i = 0; i < 4; ++i) { \
        af[0][i] = *(const bf16x8*)&_p[i * 1024 + cA0]; \
        af[1][i] = *(const bf16x8*)&_p[i * 1024 + cA1]; } }

#define READ_B(BUF, NH) { \
    const __bf16* _p = &SMEM[32768 + (BUF) * 16384 + (wn + (NH) * 32 + fr) * 64]; \
    _Pragma("unroll") for (int j = 0; j < 2; ++j) { \
        bfr[NH][0][j] = *(const bf16x8*)&_p[j * 1024 + cA0]; \
        bfr[NH][1][j] = *(const bf16x8*)&_p[j * 1024 + cA1]; } }

#define MFMAQ(MH, NH) { \
    __builtin_amdgcn_s_setprio(1); \
    _Pragma("unroll") for (int i = 0; i < 4; ++i) \
    _Pragma("unroll") for (int j = 0; j < 2; ++j) { \
        f32x4 c = acc[(MH) * 4 + i][(NH) * 2 + j]; \
        c = __builtin_amdgcn_mfma_f32_16x16x32_bf16(af[0][i], bfr[NH][0][j], c, 0, 0, 0); \
        c = __builtin_amdgcn_mfma_f32_16x16x32_bf16(af[1][i], bfr[NH][1][j], c, 0, 0, 0); \
        acc[(MH) * 4 + i][(NH) * 2 + j] = c; } \
    __builtin_amdgcn_s_setprio(0); }

#define WAITV(N) asm volatile("s_waitcnt vmcnt(" #N ")" ::: "memory")
#define BARL() { asm volatile("s_waitcnt lgkmcnt(0)" ::: "memory"); \
                 asm volatile("s_barrier" ::: "memory"); }

#define ITER4(LAST) { \
  /*P1*/ ISSUE_A(0, 1, kodd); ISSUE_B(0, 1, kodd); WAITV(6); BARL(); \
        READ_A(0, 0); READ_B(0, 0); READ_B(0, 1); MFMAQ(0, 0); MFMAQ(0, 1); \
  /*P2*/ ISSUE_B(1, 1, kodd); ISSUE_A(1, 1, kodd); WAITV(8); BARL(); \
        READ_A(0, 1); MFMAQ(1, 0); MFMAQ(1, 1); \
  /*P3*/ if (!(LAST)) { ISSUE_A(0, 0, keven); ISSUE_B(0, 0, keven); WAITV(6); } \
                       else { WAITV(2); } BARL(); \
        READ_A(1, 0); READ_B(1, 0); READ_B(1, 1); MFMAQ(0, 0); MFMAQ(0, 1); \
  /*P4*/ if (!(LAST)) { ISSUE_B(1, 0, keven); ISSUE_A(1, 0, keven); WAITV(8); } \
                       else { WAITV(0); } BARL(); \
        READ_A(1, 1); MFMAQ(1, 0); MFMAQ(1, 1); }

    // prologue: stage tile0 -> buf0 in read order A0,B0,B1,A1
    ISSUE_A(0, 0, 0); ISSUE_B(0, 0, 0); ISSUE_B(1, 0, 0); ISSUE_A(1, 0, 0);

#pragma unroll 1
    for (int it = 0; it < 7; ++it) {
        const int kodd  = it * 128 + 64;
        const int keven = it * 128 + 128;
        ITER4(0);
    }
    {
        const int kodd  = 7 * 128 + 64;
        const int keven = 0;
        ITER4(1);
    }

#undef ITER4
#undef WAITV
#undef BARL
#undef MFMAQ
#undef READ_B
#undef READ_A
#undef ISSUE_B
#undef ISSUE_A
#undef GLL16

    // ---- epilogue ----
    if (OUTMODE == 3 && n0 >= 2048) {
        // vt half: LDS-staged transpose, coalesced 16B writes.
        asm volatile("s_waitcnt lgkmcnt(0)" ::: "memory");
        __syncthreads();                       // all frag reads retired
#pragma unroll
        for (int j = 0; j < 4; ++j) {
            int dl = wn + fr + j * 16;         // d_local 0..255
#pragma unroll
            for (int i = 0; i < 8; ++i) {
                int mb = wm + quad * 4 + i * 16;   // m_local base (8B-aligned)
                bf16x4 o4;
#pragma unroll
                for (int t = 0; t < 4; ++t) o4[t] = (__bf16)acc[i][j][t];
                *(bf16x4*)&SMEM[dl * 264 + mb] = o4;
            }
        }
        __syncthreads();
        const int dcol = n0 - 2048;
#pragma unroll
        for (int it2 = 0; it2 < 16; ++it2) {
            int f = it2 * 512 + tid;
            int d = f >> 5, mseg = (f & 31) << 3;
            int gm = m0 + mseg;
            int bb = gm / 576;
            int ml = gm - bb * 576;            // run of 8 never crosses batch
            bf16x8 v = *(const bf16x8*)&SMEM[d * 264 + mseg];
            *(bf16x8*)&((__bf16*)Cp2)[((size_t)bb * 1024 + dcol + d) * 576 + ml] = v;
        }
    } else {
        // qkb half / fp32+bias: direct stores (32B+ contiguous per quarter-wave)
        const int colb = n0 + wn + fr;
        const int rowb = m0 + wm + quad * 4;
#pragma unroll
        for (int j = 0; j < 4; ++j) {
            int col = colb + j * 16;
            float bv = (OUTMODE == 0 && bias) ? bias[col] : 0.0f;
#pragma unroll
            for (int i = 0; i < 8; ++i) {
                int row = rowb + i * 16;
                if (OUTMODE == 3) {
#pragma unroll
                    for (int t = 0; t < 4; ++t)
                        ((__bf16*)Cp)[(size_t)(row + t) * 2048 + col] = (__bf16)acc[i][j][t];
                } else {
#pragma unroll
                    for (int t = 0; t < 4; ++t)
                        ((float*)Cp)[(size_t)(row + t) * N + col] = acc[i][j][t] + bv;
                }
            }
        }
    }
}

// ---------------------------------------------------------------------------
// MFMA gated attention v5r (R9-proven best). Block = (b,h), 512 threads =
// 8 waves, 2/SIMD (12 waves measured SLOWER, R7; shfl-PV measured neutral,
// R10). posf double-buffered one kb ahead. Scratch stride 56.
// LDS: 73728+73728+14336.
// ---------------------------------------------------------------------------
__global__ __launch_bounds__(512, 2) void attn_mfma3(
    const __bf16* __restrict__ qk, const __bf16* __restrict__ vt,
    const __bf16* __restrict__ Pp, const float* __restrict__ gating,
    __bf16* __restrict__ ao)
{
    __shared__ __bf16 Ks[N_ * HD_];        // [n][d], phys chunk = logical ^ (n&7)
    __shared__ __bf16 Vs[HD_ * N_];        // [d][m], phys = (l&~7)|((l&7)^(d&7))
    __shared__ __bf16 Sc[8 * 16 * 56];     // per-wave scratch [16][56]

    const int bid = blockIdx.x;
    const int h = bid & 15, b = bid >> 4;
    const int tid = threadIdx.x;
    const int lane = tid & 63, wave = tid >> 6;   // 0..7
    const int fr = lane & 15, quad = lane >> 4;

    const __bf16* qbase = qk + (size_t)b * N_ * (2 * D_) + h * HD_;
    const __bf16* kgl   = qbase + D_;
    const __bf16* vgl   = vt + (size_t)(b * H_ + h) * HD_ * N_;

#pragma unroll 3
    for (int it = 0; it < 9; ++it) {
        int s = it * 512 + tid;
        int r = s >> 3, p = s & 7;
        int l = p ^ (r & 7);
        __builtin_amdgcn_global_load_lds(
            (const __attribute__((address_space(1))) void*)(kgl + (size_t)r * (2 * D_) + l * 8),
            (__attribute__((address_space(3))) void*)&Ks[(size_t)(it * 512 + wave * 64) * 8],
            16, 0, 0);
        int d = s / 72, pv = s - d * 72;
        int lv = (pv & ~7) | ((pv & 7) ^ (d & 7));
        __builtin_amdgcn_global_load_lds(
            (const __attribute__((address_space(1))) void*)(vgl + (size_t)d * N_ + lv * 8),
            (__attribute__((address_space(3))) void*)&Vs[(size_t)(it * 512 + wave * 64) * 8],
            16, 0, 0);
    }
    __syncthreads();

    const float g   = 1.f / (1.f + __expf(-gating[h]));
    const float omg = 1.f - g;
    const float kk = 0.125f * LOG2E;

    __bf16* sw = &Sc[wave * 16 * 56];

    for (int tt = wave; tt < 36; tt += 8) {
        const int n0 = tt * 16;

        const __bf16* qp = qbase + (size_t)(n0 + fr) * (2 * D_) + quad * 8;
        bf16x8 qf0 = *(const bf16x8*)qp;
        bf16x8 qf1 = *(const bf16x8*)(qp + 32);

        const __bf16* pprow = Pp + ((size_t)h * N_ + n0 + fr) * N_ + quad * 8;

        f32x4 S[36];
#pragma unroll
        for (int ct = 0; ct < 36; ++ct) {
            int row = ct * 16 + fr;
            int p0 = quad ^ (row & 7);
            int p1 = (4 + quad) ^ (row & 7);
            bf16x8 k0 = *(const bf16x8*)&Ks[row * 64 + p0 * 8];
            bf16x8 k1 = *(const bf16x8*)&Ks[row * 64 + p1 * 8];
            f32x4 a = (f32x4){0.f, 0.f, 0.f, 0.f};
            a = __builtin_amdgcn_mfma_f32_16x16x32_bf16(qf0, k0, a, 0, 0, 0);
            a = __builtin_amdgcn_mfma_f32_16x16x32_bf16(qf1, k1, a, 0, 0, 0);
            S[ct] = a;
        }

        float inv[4];
#pragma unroll
        for (int t = 0; t < 4; ++t) {
            float mt[18];
#pragma unroll
            for (int i = 0; i < 18; ++i) mt[i] = fmaxf(S[i][t], S[i + 18][t]);
#pragma unroll
            for (int i = 0; i < 9; ++i) mt[i] = fmaxf(mt[i], mt[i + 9]);
            float m = fmaxf(fmaxf(fmaxf(mt[0], mt[1]), fmaxf(mt[2], mt[3])),
                            fmaxf(fmaxf(fmaxf(mt[4], mt[5]), fmaxf(mt[6], mt[7])), mt[8]));
            m = fmaxf(m, __shfl_xor(m, 1, 16));
            m = fmaxf(m, __shfl_xor(m, 2, 16));
            m = fmaxf(m, __shfl_xor(m, 4, 16));
            m = fmaxf(m, __shfl_xor(m, 8, 16));
            float km = kk * m;
            float s0 = 0.f, s1 = 0.f, s2 = 0.f, s3 = 0.f;
#pragma unroll
            for (int ct = 0; ct < 36; ++ct) {
                float e = __builtin_amdgcn_exp2f(fmaf(kk, S[ct][t], -km));
                S[ct][t] = e;
                if ((ct & 3) == 0)      s0 += e;
                else if ((ct & 3) == 1) s1 += e;
                else if ((ct & 3) == 2) s2 += e;
                else                    s3 += e;
            }
            float s = (s0 + s1) + (s2 + s3);
            s += __shfl_xor(s, 1, 16);
            s += __shfl_xor(s, 2, 16);
            s += __shfl_xor(s, 4, 16);
            s += __shfl_xor(s, 8, 16);
            inv[t] = omg / s;
        }

        f32x4 O[4];
#pragma unroll
        for (int dt = 0; dt < 4; ++dt) O[dt] = (f32x4){0.f, 0.f, 0.f, 0.f};

        bf16x8 posf = *(const bf16x8*)pprow;   // kb=0 fragment
#pragma unroll
        for (int kb = 0; kb < 18; ++kb) {
            bf16x8 posf_nxt = posf;
            if (kb < 17) posf_nxt = *(const bf16x8*)(pprow + (kb + 1) * 32);
#pragma unroll
            for (int ctl = 0; ctl < 2; ++ctl) {
                int ct = 2 * kb + ctl;
#pragma unroll
                for (int t = 0; t < 4; ++t) {
                    float pval = S[ct][t] * inv[t];
                    sw[(quad * 4 + t) * 56 + ctl * 16 + fr] = (__bf16)pval;
                }
            }
            bf16x8 pf = *(const bf16x8*)&sw[fr * 56 + quad * 8];
#pragma unroll
            for (int dt = 0; dt < 4; ++dt) {
                int d = dt * 16 + fr;
                int l = kb * 4 + quad;
                int p = (l & ~7) | ((l & 7) ^ (d & 7));
                bf16x8 vf = *(const bf16x8*)&Vs[d * 576 + p * 8];
                O[dt] = __builtin_amdgcn_mfma_f32_16x16x32_bf16(vf, pf,   O[dt], 0, 0, 0);
                O[dt] = __builtin_amdgcn_mfma_f32_16x16x32_bf16(vf, posf, O[dt], 0, 0, 0);
            }
            posf = posf_nxt;
        }

        asm volatile("s_waitcnt lgkmcnt(0)" ::: "memory");
#pragma unroll
        for (int ps = 0; ps < 2; ++ps) {
#pragma unroll
            for (int dh = 0; dh < 2; ++dh) {
                int dt = 2 * ps + dh;
                bf16x4 o4;
#pragma unroll
                for (int t = 0; t < 4; ++t) o4[t] = (__bf16)O[dt][t];
                *(bf16x4*)&sw[fr * 56 + dh * 16 + quad * 4] = o4;
            }
            asm volatile("s_waitcnt lgkmcnt(0)" ::: "memory");
            {
                int row = lane >> 2;
                int off = (lane & 3) * 8;
                bf16x8 ov = *(const bf16x8*)&sw[row * 56 + off];
                *(bf16x8*)&ao[((size_t)b * N_ + n0 + row) * D_ + h * HD_ + ps * 32 + off] = ov;
            }
            asm volatile("s_waitcnt lgkmcnt(0)" ::: "memory");
        }
    }
}

// ---------------------------------------------------------------------------
extern "C" void kernel_launch(void* const* d_in, const int* in_sizes, int n_in,
                              void* d_out, int out_size, void* d_ws, size_t ws_size,
                              hipStream_t stream)
{
    const float* x      = (const float*)d_in[0];
    const float* W_qk   = (const float*)d_in[1];
    const float* W_v    = (const float*)d_in[2];
    const float* W_proj = (const float*)d_in[3];
    const float* b_proj = (const float*)d_in[4];
    const float* W_pos  = (const float*)d_in[5];
    const float* b_pos  = (const float*)d_in[6];   // unused: cancels in softmax
    const float* gating = (const float*)d_in[7];
    const float* rel    = (const float*)d_in[8];   // unused: computed on the fly
    (void)b_pos; (void)rel;
    float* out = (float*)d_out;

    // workspace carve (~114 MB)
    char* p = (char*)d_ws;
    __bf16* xb    = (__bf16*)p;  p += (size_t)BN_ * D_ * 2;            // 18.9 MB
    __bf16* wqkvt = (__bf16*)p;  p += (size_t)(3 * D_) * D_ * 2;       //  6.3 MB
    __bf16* wpt   = (__bf16*)p;  p += (size_t)D_ * D_ * 2;             //  2.1 MB
    __bf16* qkb   = (__bf16*)p;  p += (size_t)BN_ * (2 * D_) * 2;      // 37.7 MB
    __bf16* vt    = (__bf16*)p;  p += (size_t)BN_ * D_ * 2;            // 18.9 MB [b,h,d,m]
    __bf16* aob   = (__bf16*)p;  p += (size_t)BN_ * D_ * 2;            // 18.9 MB
    __bf16* Pp    = (__bf16*)p;                                        // 10.6 MB [h,n,m]

    // fused prep: cast + 3 transposes + pos softmax (one launch)
    prep<<<12544, 256, 0, stream>>>(x, W_qk, W_v, W_proj, W_pos, gating,
                                    xb, wqkvt, wpt, Pp);
    // fused qk|v GEMM: N=3072; cols<2048 -> qkb, cols>=2048 -> vt (transposed)
    gemm256<3><<<dim3((BN_ / 256) * (3 * D_ / 256)), 512, 0, stream>>>(
        xb, wqkvt, nullptr, qkb, vt, BN_, 3 * D_, 3 * D_ / 256);
    attn_mfma3<<<B_ * H_, 512, 0, stream>>>(qkb, vt, Pp, gating, aob);
    gemm256<0><<<dim3((BN_ / 256) * (D_ / 256)), 512, 0, stream>>>(
        aob, wpt, b_proj, out, nullptr, BN_, D_, D_ / 256);
}